// Round 14
// baseline (481.939 us; speedup 1.0000x reference)
//
#include <hip/hip_runtime.h>
#include <math.h>

#define TSEQ 512
#define FDIM 64
#define HDIM 128
#define NB   512

// prescales folded into weights/biases so activations use raw exp2
#define SR 1.4426950408889634f   // log2(e)   : r,z gates
#define SN 2.8853900817779268f   // 2*log2(e) : n gate

typedef _Float16 f16x8 __attribute__((ext_vector_type(8)));
typedef _Float16 f16x4 __attribute__((ext_vector_type(4)));
typedef __fp16  fp16x2 __attribute__((ext_vector_type(2)));
typedef __attribute__((ext_vector_type(4))) float f32x4;

#define H_ROW 136                 // halves per batch row (+8 pad)
#define H_BUF (16 * H_ROW)
#define S_ROW 260                 // floats per batch row of sigma buf (16B-aligned, bank-spread)

#if __has_builtin(__builtin_amdgcn_mfma_f32_16x16x16f16)
#define HAVE_MFMA16K16 1
__device__ __forceinline__ f32x4 mfma16k16(f16x4 a, f16x4 b, f32x4 c) {
    return __builtin_amdgcn_mfma_f32_16x16x16f16(a, b, c, 0, 0, 0);
}
#elif __has_builtin(__builtin_amdgcn_mfma_f32_16x16x16_f16)
#define HAVE_MFMA16K16 1
__device__ __forceinline__ f32x4 mfma16k16(f16x4 a, f16x4 b, f32x4 c) {
    return __builtin_amdgcn_mfma_f32_16x16x16_f16(a, b, c, 0, 0, 0);
}
#else
#define HAVE_MFMA16K16 0
#endif

__device__ __forceinline__ float exp2_hw(float x) {
#if __has_builtin(__builtin_amdgcn_exp2f)
    return __builtin_amdgcn_exp2f(x);
#else
    return exp2f(x);
#endif
}
__device__ __forceinline__ float fast_tanh(float x) {   // out_final / fallback
    return 1.0f - 2.0f * __builtin_amdgcn_rcpf(1.0f + exp2_hw(SN * x));
}
__device__ __forceinline__ f32x4 mfma16f(f16x8 a, f16x8 b, f32x4 c) {
    return __builtin_amdgcn_mfma_f32_16x16x32_f16(a, b, c, 0, 0, 0);
}

union PU { fp16x2 h2[4]; f16x8 v; };
union GU { uint2 u; _Float16 h[4]; f16x4 v; };

__device__ __forceinline__ f16x8 pack_f16(float4 a, float4 b) {
    PU u;
    u.h2[0] = __builtin_amdgcn_cvt_pkrtz(a.x, a.y);
    u.h2[1] = __builtin_amdgcn_cvt_pkrtz(a.z, a.w);
    u.h2[2] = __builtin_amdgcn_cvt_pkrtz(b.x, b.y);
    u.h2[3] = __builtin_amdgcn_cvt_pkrtz(b.z, b.w);
    return u.v;
}

// Raw barrier: drain LDS only. Global loads/stores (vmcnt) stay in flight.
__device__ __forceinline__ void wg_barrier() {
    __builtin_amdgcn_sched_barrier(0);
    asm volatile("s_waitcnt lgkmcnt(0)" ::: "memory");
    __builtin_amdgcn_s_barrier();
    asm volatile("" ::: "memory");
    __builtin_amdgcn_sched_barrier(0);
}

// ---------------- pre-GEMM: gi (fp16, prescaled, biases folded) -----------
// gi as uint2[TSEQ][96][NB]; x tile LDS-staged with coalesced loads.
__global__ __launch_bounds__(512)
void gi_gemm16(const float* __restrict__ x,
               const float* __restrict__ W_ih,
               const float* __restrict__ b_ih,
               const float* __restrict__ b_hh,
               uint2* __restrict__ gi)
{
    const int tid  = threadIdx.x;
    const int w    = tid >> 6;
    const int lane = tid & 63;
    const int g4   = lane >> 4;
    const int bcol = lane & 15;
    const int b0   = blockIdx.x * 16;
    const int t0   = blockIdx.y * 16;

    __shared__ __align__(16) _Float16 xt[16 * 1032 + 8];

    {
        const int bl = tid >> 5, q = tid & 31;
        const float* xp = x + ((size_t)(b0 + bl) * TSEQ + t0) * FDIM;
        _Float16* dst = &xt[bl * 1032];
        #pragma unroll
        for (int j = 0; j < 8; ++j) {
            float4 v = *(const float4*)(xp + j * 128 + q * 4);
            union { fp16x2 p[2]; uint2 u; } pu;
            pu.p[0] = __builtin_amdgcn_cvt_pkrtz(v.x, v.y);
            pu.p[1] = __builtin_amdgcn_cvt_pkrtz(v.z, v.w);
            *(uint2*)&dst[j * 128 + q * 4] = pu.u;
        }
    }

    f16x8 WihF[3][2];
    #pragma unroll
    for (int kd = 0; kd < 3; ++kd) {
        const float sc = (kd < 2) ? SR : SN;
        const int g = kd * 128 + w * 16 + bcol;
        #pragma unroll
        for (int kt = 0; kt < 2; ++kt) {
            const float* pw = W_ih + g * FDIM + kt * 32 + g4 * 8;
            f16x8 v;
            #pragma unroll
            for (int e = 0; e < 8; ++e) v[e] = (_Float16)(pw[e] * sc);
            WihF[kd][kt] = v;
        }
    }
    f32x4 biasR, biasZ, biasN;
    #pragma unroll
    for (int i = 0; i < 4; ++i) {
        const int gr = w * 16 + g4 * 4 + i;
        biasR[i] = (b_ih[gr]       + b_hh[gr])       * SR;
        biasZ[i] = (b_ih[128 + gr] + b_hh[128 + gr]) * SR;
        biasN[i] = b_ih[256 + gr] * SN;
    }
    __syncthreads();

    for (int tt = 0; tt < 16; ++tt) {
        const _Float16* xr = &xt[bcol * 1032 + tt * 64];
        f16x8 xf0 = *(const f16x8*)(xr + g4 * 8);
        f16x8 xf1 = *(const f16x8*)(xr + 32 + g4 * 8);

        f32x4 c0 = biasR, c1 = biasZ, c2 = biasN;
        c0 = mfma16f(WihF[0][0], xf0, c0);
        c0 = mfma16f(WihF[0][1], xf1, c0);
        c1 = mfma16f(WihF[1][0], xf0, c1);
        c1 = mfma16f(WihF[1][1], xf1, c1);
        c2 = mfma16f(WihF[2][0], xf0, c2);
        c2 = mfma16f(WihF[2][1], xf1, c2);

        GU g0, g1, g2;
        #pragma unroll
        for (int i = 0; i < 4; ++i) {
            g0.h[i] = (_Float16)c0[i];
            g1.h[i] = (_Float16)c1[i];
            g2.h[i] = (_Float16)c2[i];
        }
        const int t = t0 + tt;
        const size_t base = ((size_t)t * 96 + w * 4 + g4) * NB + (b0 + bcol);
        gi[base]           = g0.u;
        gi[base + 32 * NB] = g1.u;
        gi[base + 64 * NB] = g2.u;
    }
}

// ---------------- out finalize: out[b][t] = tanh(sum(pp) + b_out) ---------
__global__ __launch_bounds__(512)
void out_final(const float* __restrict__ pp,
               const float* __restrict__ b_out,
               float* __restrict__ out)
{
    const int t = blockIdx.x;
    const int b = threadIdx.x;
    float acc = b_out[0];
    const float* p = pp + (size_t)t * 32 * NB + b;
    #pragma unroll
    for (int c = 0; c < 32; ++c) acc += p[(size_t)c * NB];
    out[(size_t)b * TSEQ + t] = fast_tanh(acc);
}

// ---------------- recurrence: main/shadow split ----------------------------
// 32 blocks x 16 batches, 1024 threads = 16 waves (4/SIMD).
// Shadow wave s (wid 8..15, s=wid-8): a0,a1 for rows [16s,16s+16) (8 MFMA +
//   2 injects) + sigmoids (16 trans ops) -> sig_s[wb] (f32, exact).
// Main wave w (wid 0..7): phase1 a3 (4 MFMA) + a2 inject; after mid barrier
//   reads sigma, n-gate (8 trans), h update, h/psum writes.
// Two top-level barriers/step; h and sigma triple-buffered (>=3 barriers
// between any RAW/WAR pair). psum partials fire-and-forget to pp.
__global__ __launch_bounds__(1024, 4)
void gru_split(const float* __restrict__ W_hh,
               const float* __restrict__ b_hh,
               const float* __restrict__ W_out,
               const uint2* __restrict__ gi,
               float* __restrict__ pp)
{
    const int tid  = threadIdx.x;
    const int wid  = tid >> 6;          // 0..15
    const int lane = tid & 63;
    const int g4   = lane >> 4;
    const int bcol = lane & 15;
    const int b0   = blockIdx.x * 16;
    const bool is_main = (wid < 8);
    const int w = wid & 7;

    __shared__ __align__(16) _Float16 h_s[3][16][H_ROW];
    __shared__ __align__(16) float sig_s[3][16][S_ROW];

    // identity A-fragment for 16x16x16 inject
    f16x4 iden;
    #pragma unroll
    for (int e = 0; e < 4; ++e)
        iden[e] = (bcol == g4 * 4 + e) ? (_Float16)1.0f : (_Float16)0.0f;
    const f32x4 zero4 = {0.f, 0.f, 0.f, 0.f};

    // ---- stationary weights ----
    f16x8 WhhA[4], WhhB[4];             // main: A = n-kind; shadow: A=r, B=z
    f32x4 biasNH = zero4;
    float wout_r[4], h_old[4];
    if (is_main) {
        const int g = 256 + w * 16 + bcol;
        #pragma unroll
        for (int kt = 0; kt < 4; ++kt) {
            const float* pw = W_hh + g * HDIM + kt * 32 + g4 * 8;
            f16x8 v;
            #pragma unroll
            for (int e = 0; e < 8; ++e) v[e] = (_Float16)(pw[e] * SN);
            WhhA[kt] = v;
        }
        #pragma unroll
        for (int i = 0; i < 4; ++i) {
            const int gr = w * 16 + g4 * 4 + i;
            biasNH[i] = b_hh[256 + gr] * SN;
            wout_r[i] = W_out[gr];
            h_old[i]  = 0.0f;
        }
    } else {
        const int gr_ = w * 16 + bcol;          // r rows
        const int gz_ = 128 + w * 16 + bcol;    // z rows
        #pragma unroll
        for (int kt = 0; kt < 4; ++kt) {
            const float* pr = W_hh + gr_ * HDIM + kt * 32 + g4 * 8;
            const float* pz = W_hh + gz_ * HDIM + kt * 32 + g4 * 8;
            f16x8 vr, vz;
            #pragma unroll
            for (int e = 0; e < 8; ++e) {
                vr[e] = (_Float16)(pr[e] * SR);
                vz[e] = (_Float16)(pz[e] * SR);
            }
            WhhA[kt] = vr; WhhB[kt] = vz;
        }
    }

    {   // zero h buffer 0
        unsigned* hp = (unsigned*)&h_s[0][0][0];
        for (int i = tid; i < H_BUF / 2; i += 1024) hp[i] = 0u;
    }

    // ---- gi pipelines: 4 slots, 4 steps ahead ----
    GU a0s, a1s, a2s, a3s;              // stream A (main: n; shadow: r)
    GU b0s, b1s, b2s, b3s;              // stream B (shadow: z)
    const uint2* gA;
    const uint2* gZ = nullptr;
    float* ppp = nullptr;
    if (is_main) {
        gA  = gi + (size_t)(64 + w * 4 + g4) * NB + (b0 + bcol);
        ppp = pp + (size_t)(w * 4 + g4) * NB + (b0 + bcol);
    } else {
        gA = gi + (size_t)(w * 4 + g4) * NB + (b0 + bcol);
        gZ = gA + (size_t)32 * NB;
    }
    a0s.u = gA[0];
    a1s.u = gA[(size_t)96  * NB];
    a2s.u = gA[(size_t)192 * NB];
    a3s.u = gA[(size_t)288 * NB];
    if (!is_main) {
        b0s.u = gZ[0];
        b1s.u = gZ[(size_t)96  * NB];
        b2s.u = gZ[(size_t)192 * NB];
        b3s.u = gZ[(size_t)288 * NB];
    }

    __syncthreads();   // prologue barrier

    const int sigoff = (w * 4 + g4) * 8;
    int rb = 0, wb = 1;

#if HAVE_MFMA16K16
#define INJ(S) mfma16k16(iden, S.v, zero4)
#else
#define INJ(S) (f32x4){(float)S.h[0], (float)S.h[1], (float)S.h[2], (float)S.h[3]}
#endif
#define RFA(S) if (s + 4 < TSEQ) S.u = gA[(size_t)(s + 4) * 96 * NB];
#define RFZ(S) if (s + 4 < TSEQ) S.u = gZ[(size_t)(s + 4) * 96 * NB];

    for (int t = 0; t < TSEQ; t += 4) {
        #pragma unroll
        for (int u = 0; u < 4; ++u) {
            const int s = t + u;

            f16x8 bh0 = *(const f16x8*)&h_s[rb][bcol][0 * 32 + g4 * 8];
            f16x8 bh1 = *(const f16x8*)&h_s[rb][bcol][1 * 32 + g4 * 8];
            f16x8 bh2 = *(const f16x8*)&h_s[rb][bcol][2 * 32 + g4 * 8];
            f16x8 bh3 = *(const f16x8*)&h_s[rb][bcol][3 * 32 + g4 * 8];

            f32x4 a2 = zero4, a3 = zero4;

            if (is_main) {
                // ---- main phase 1: a2 inject + a3 MFMA chain ----
                if (u == 0)      { a2 = INJ(a0s); RFA(a0s) }
                else if (u == 1) { a2 = INJ(a1s); RFA(a1s) }
                else if (u == 2) { a2 = INJ(a2s); RFA(a2s) }
                else             { a2 = INJ(a3s); RFA(a3s) }
                a3 = biasNH;
                a3 = mfma16f(WhhA[0], bh0, a3);
                a3 = mfma16f(WhhA[1], bh1, a3);
                a3 = mfma16f(WhhA[2], bh2, a3);
                a3 = mfma16f(WhhA[3], bh3, a3);
            } else {
                // ---- shadow phase 1: a0,a1 + sigmoids -> sig_s[wb] ----
                f32x4 a0, a1;
                if (u == 0)      { a0 = INJ(a0s); a1 = INJ(b0s); RFA(a0s) RFZ(b0s) }
                else if (u == 1) { a0 = INJ(a1s); a1 = INJ(b1s); RFA(a1s) RFZ(b1s) }
                else if (u == 2) { a0 = INJ(a2s); a1 = INJ(b2s); RFA(a2s) RFZ(b2s) }
                else             { a0 = INJ(a3s); a1 = INJ(b3s); RFA(a3s) RFZ(b3s) }
                a0 = mfma16f(WhhA[0], bh0, a0);
                a1 = mfma16f(WhhB[0], bh0, a1);
                a0 = mfma16f(WhhA[1], bh1, a0);
                a1 = mfma16f(WhhB[1], bh1, a1);
                a0 = mfma16f(WhhA[2], bh2, a0);
                a1 = mfma16f(WhhB[2], bh2, a1);
                a0 = mfma16f(WhhA[3], bh3, a0);
                a1 = mfma16f(WhhB[3], bh3, a1);
                f32x4 rv, zv;
                #pragma unroll
                for (int i = 0; i < 4; ++i) {
                    rv[i] = __builtin_amdgcn_rcpf(1.0f + exp2_hw(-a0[i]));
                    zv[i] = __builtin_amdgcn_rcpf(1.0f + exp2_hw(-a1[i]));
                }
                *(f32x4*)&sig_s[wb][bcol][sigoff]     = rv;
                *(f32x4*)&sig_s[wb][bcol][sigoff + 4] = zv;
            }

            wg_barrier();   // B2: sigma[wb] visible; all h[rb] reads done

            if (is_main) {
                // ---- main phase 2: n-gate, h update, writes ----
                f32x4 rv = *(const f32x4*)&sig_s[wb][bcol][sigoff];
                f32x4 zv = *(const f32x4*)&sig_s[wb][bcol][sigoff + 4];
                float psum = 0.0f;
                _Float16 h16[4];
                #pragma unroll
                for (int i = 0; i < 4; ++i) {
                    float y  = fmaf(rv[i], a3[i], a2[i]);
                    float n  = fmaf(-2.0f,
                                    __builtin_amdgcn_rcpf(1.0f + exp2_hw(y)),
                                    1.0f);
                    float hn = fmaf(zv[i], h_old[i] - n, n);
                    h_old[i] = hn;
                    h16[i]   = (_Float16)hn;
                    psum = fmaf(wout_r[i], hn, psum);
                }
                union { _Float16 h[4]; uint2 u; } hu;
                hu.h[0] = h16[0]; hu.h[1] = h16[1];
                hu.h[2] = h16[2]; hu.h[3] = h16[3];
                *(uint2*)&h_s[wb][bcol][w * 16 + g4 * 4] = hu.u;
                *ppp = psum;                  // fire-and-forget partial
                ppp += 32 * NB;
            }

            wg_barrier();   // B1: h[wb] visible for next step
            rb = wb; wb = (wb == 2) ? 0 : wb + 1;
        }
    }
#undef INJ
#undef RFA
#undef RFZ
}

// ---------------- fallback (no workspace): R9-proven unified kernel -------
__global__ __launch_bounds__(512, 2)
void gru_fb(const float* __restrict__ x,
            const float* __restrict__ W_ih,
            const float* __restrict__ W_hh,
            const float* __restrict__ b_ih,
            const float* __restrict__ b_hh,
            const float* __restrict__ W_out,
            const float* __restrict__ b_out,
            float* __restrict__ out)
{
    const int tid  = threadIdx.x;
    const int wid  = tid >> 6;
    const int lane = tid & 63;
    const int g4   = lane >> 4;
    const int bcol = lane & 15;
    const int b0   = blockIdx.x * 16;

    __shared__ __align__(16) _Float16 h_s[3][16][H_ROW];
    __shared__ __align__(16) float ps_s[3][16][12];

    f16x8 WhhF[3][4];
    f16x8 WihF[3][2];
    #pragma unroll
    for (int kd = 0; kd < 3; ++kd) {
        const float sc = (kd < 2) ? SR : SN;
        const int g = kd * 128 + wid * 16 + bcol;
        #pragma unroll
        for (int kt = 0; kt < 4; ++kt) {
            const float* pw = W_hh + g * HDIM + kt * 32 + g4 * 8;
            f16x8 v;
            #pragma unroll
            for (int e = 0; e < 8; ++e) v[e] = (_Float16)(pw[e] * sc);
            WhhF[kd][kt] = v;
        }
        #pragma unroll
        for (int kt = 0; kt < 2; ++kt) {
            const float* pw = W_ih + g * FDIM + kt * 32 + g4 * 8;
            f16x8 v;
            #pragma unroll
            for (int e = 0; e < 8; ++e) v[e] = (_Float16)(pw[e] * sc);
            WihF[kd][kt] = v;
        }
    }

    f32x4 biasR, biasZ, biasNI, biasNH;
    float wout_r[4], h_old[4];
    #pragma unroll
    for (int i = 0; i < 4; ++i) {
        const int gr = wid * 16 + g4 * 4 + i;
        biasR[i]  = (b_ih[gr]       + b_hh[gr])       * SR;
        biasZ[i]  = (b_ih[128 + gr] + b_hh[128 + gr]) * SR;
        biasNI[i] = b_ih[256 + gr] * SN;
        biasNH[i] = b_hh[256 + gr] * SN;
        wout_r[i] = W_out[gr];
        h_old[i]  = 0.0f;
    }
    const float bout = b_out[0];

    {
        unsigned* hp = (unsigned*)&h_s[0][0][0];
        for (int i = tid; i < H_BUF / 2; i += 512) hp[i] = 0u;
    }

    const float* xb = x + (size_t)(b0 + bcol) * TSEQ * FDIM;
    float4 sA0, sA1, sA2, sA3, sB0, sB1, sB2, sB3;
    sA0 = *(const float4*)(xb + g4 * 8);
    sA1 = *(const float4*)(xb + g4 * 8 + 4);
    sA2 = *(const float4*)(xb + 32 + g4 * 8);
    sA3 = *(const float4*)(xb + 32 + g4 * 8 + 4);
    {
        const float* xp1 = xb + FDIM;
        sB0 = *(const float4*)(xp1 + g4 * 8);
        sB1 = *(const float4*)(xp1 + g4 * 8 + 4);
        sB2 = *(const float4*)(xp1 + 32 + g4 * 8);
        sB3 = *(const float4*)(xp1 + 32 + g4 * 8 + 4);
    }
    f16x8 xf0 = pack_f16(sA0, sA1);
    f16x8 xf1 = pack_f16(sA2, sA3);

    __syncthreads();

    const bool outw = (wid == 0) && (lane < 16);
    float* outp = out + (size_t)(b0 + lane) * TSEQ;
    float o0 = 0.f, o1 = 0.f, o2 = 0.f, o3 = 0.f;
    int rb = 0, wb = 1;

    for (int t = 0; t < TSEQ; t += 4) {
        #pragma unroll
        for (int u = 0; u < 4; ++u) {
            const int s = t + u;

            if (outw && s > 0) {
                f32x4 q0 = *(const f32x4*)&ps_s[rb][lane][0];
                f32x4 q1 = *(const f32x4*)&ps_s[rb][lane][4];
                float sm = (q0[0] + q0[1]) + (q0[2] + q0[3])
                         + (q1[0] + q1[1]) + (q1[2] + q1[3]);
                float val = fast_tanh(sm + bout);
                if (u == 0) {
                    o3 = val;
                    *(float4*)(outp + (t - 4)) = make_float4(o0, o1, o2, o3);
                } else if (u == 1) o0 = val;
                else if (u == 2) o1 = val;
                else o2 = val;
            }

            {
                const int tl = (s + 2 < TSEQ) ? (s + 2) : (TSEQ - 1);
                const float* xp = xb + (size_t)tl * FDIM;
                if ((u & 1) == 0) {
                    sA0 = *(const float4*)(xp + g4 * 8);
                    sA1 = *(const float4*)(xp + g4 * 8 + 4);
                    sA2 = *(const float4*)(xp + 32 + g4 * 8);
                    sA3 = *(const float4*)(xp + 32 + g4 * 8 + 4);
                } else {
                    sB0 = *(const float4*)(xp + g4 * 8);
                    sB1 = *(const float4*)(xp + g4 * 8 + 4);
                    sB2 = *(const float4*)(xp + 32 + g4 * 8);
                    sB3 = *(const float4*)(xp + 32 + g4 * 8 + 4);
                }
            }
            f16x8 bh0 = *(const f16x8*)&h_s[rb][bcol][0 * 32 + g4 * 8];
            f16x8 bh1 = *(const f16x8*)&h_s[rb][bcol][1 * 32 + g4 * 8];
            f16x8 bh2 = *(const f16x8*)&h_s[rb][bcol][2 * 32 + g4 * 8];
            f16x8 bh3 = *(const f16x8*)&h_s[rb][bcol][3 * 32 + g4 * 8];

            f32x4 a0 = biasR, a1 = biasZ, a2 = biasNI, a3 = biasNH;
            a0 = mfma16f(WihF[0][0], xf0, a0);
            a0 = mfma16f(WihF[0][1], xf1, a0);
            a1 = mfma16f(WihF[1][0], xf0, a1);
            a1 = mfma16f(WihF[1][1], xf1, a1);
            a2 = mfma16f(WihF[2][0], xf0, a2);
            a2 = mfma16f(WihF[2][1], xf1, a2);

            a0 = mfma16f(WhhF[0][0], bh0, a0);
            a1 = mfma16f(WhhF[1][0], bh0, a1);
            a3 = mfma16f(WhhF[2][0], bh0, a3);
            a0 = mfma16f(WhhF[0][1], bh1, a0);
            a1 = mfma16f(WhhF[1][1], bh1, a1);
            a3 = mfma16f(WhhF[2][1], bh1, a3);
            a0 = mfma16f(WhhF[0][2], bh2, a0);
            a1 = mfma16f(WhhF[1][2], bh2, a1);
            a3 = mfma16f(WhhF[2][2], bh2, a3);
            a0 = mfma16f(WhhF[0][3], bh3, a0);
            a1 = mfma16f(WhhF[1][3], bh3, a1);
            a3 = mfma16f(WhhF[2][3], bh3, a3);

            float psum = 0.0f;
            _Float16 h16[4];
            #pragma unroll
            for (int i = 0; i < 4; ++i) {
                float r  = __builtin_amdgcn_rcpf(1.0f + exp2_hw(-a0[i]));
                float z  = __builtin_amdgcn_rcpf(1.0f + exp2_hw(-a1[i]));
                float y  = fmaf(r, a3[i], a2[i]);
                float n  = fmaf(-2.0f,
                                __builtin_amdgcn_rcpf(1.0f + exp2_hw(y)), 1.0f);
                float hn = fmaf(z, h_old[i] - n, n);
                h_old[i] = hn;
                h16[i]   = (_Float16)hn;
                psum = fmaf(wout_r[i], hn, psum);
            }

            union { _Float16 h[4]; uint2 u; } hu;
            hu.h[0] = h16[0]; hu.h[1] = h16[1];
            hu.h[2] = h16[2]; hu.h[3] = h16[3];
            *(uint2*)&h_s[wb][bcol][wid * 16 + g4 * 4] = hu.u;

            psum += __shfl_xor(psum, 16);
            psum += __shfl_xor(psum, 32);
            if (lane < 16) ps_s[wb][lane][wid] = psum;

            if ((u & 1) == 0) {
                xf0 = pack_f16(sB0, sB1);
                xf1 = pack_f16(sB2, sB3);
            } else {
                xf0 = pack_f16(sA0, sA1);
                xf1 = pack_f16(sA2, sA3);
            }

            wg_barrier();
            rb = wb; wb = (wb == 2) ? 0 : wb + 1;
        }
    }

    if (outw) {
        f32x4 q0 = *(const f32x4*)&ps_s[2][lane][0];
        f32x4 q1 = *(const f32x4*)&ps_s[2][lane][4];
        float sm = (q0[0] + q0[1]) + (q0[2] + q0[3])
                 + (q1[0] + q1[1]) + (q1[2] + q1[3]);
        o3 = fast_tanh(sm + bout);
        *(float4*)(outp + (TSEQ - 4)) = make_float4(o0, o1, o2, o3);
    }
}

extern "C" void kernel_launch(void* const* d_in, const int* in_sizes, int n_in,
                              void* d_out, int out_size, void* d_ws, size_t ws_size,
                              hipStream_t stream) {
    const float* x     = (const float*)d_in[0];
    const float* W_ih  = (const float*)d_in[1];
    const float* W_hh  = (const float*)d_in[2];
    const float* b_ih  = (const float*)d_in[3];
    const float* b_hh  = (const float*)d_in[4];
    const float* W_out = (const float*)d_in[5];
    const float* b_out = (const float*)d_in[6];
    float* out = (float*)d_out;

    const size_t gi_bytes = (size_t)TSEQ * NB * 384 * sizeof(_Float16); // 201.3 MB
    const size_t pp_bytes = (size_t)TSEQ * 32 * NB * sizeof(float);     // 33.6 MB

    if (ws_size >= gi_bytes + pp_bytes) {
        uint2* gi = (uint2*)d_ws;
        float* pp = (float*)((char*)d_ws + gi_bytes);
        gi_gemm16<<<dim3(32, 32), 512, 0, stream>>>(x, W_ih, b_ih, b_hh, gi);
        gru_split<<<32, 1024, 0, stream>>>(W_hh, b_hh, W_out, gi, pp);
        out_final<<<TSEQ, NB, 0, stream>>>(pp, b_out, out);
    } else {
        gru_fb<<<32, 512, 0, stream>>>(x, W_ih, W_hh, b_ih, b_hh,
                                       W_out, b_out, out);
    }
}

// Round 15
// 341.333 us; speedup vs baseline: 1.4119x; 1.4119x over previous
//
#include <hip/hip_runtime.h>
#include <math.h>

#define TSEQ 512
#define FDIM 64
#define HDIM 128
#define NB   512

// prescales folded into weights/biases so activations use raw exp2
#define SR 1.4426950408889634f   // log2(e)   : r,z gates
#define SN 2.8853900817779268f   // 2*log2(e) : n gate

typedef _Float16 f16x8 __attribute__((ext_vector_type(8)));
typedef _Float16 f16x4 __attribute__((ext_vector_type(4)));
typedef __fp16  fp16x2 __attribute__((ext_vector_type(2)));
typedef __attribute__((ext_vector_type(4))) float f32x4;

#define H_ROW 136                 // halves per batch row (+8 pad)
#define H_BUF (16 * H_ROW)
#define G_STEP ((size_t)96 * NB)  // uint2 elements per timestep of gi

#if __has_builtin(__builtin_amdgcn_mfma_f32_16x16x16f16)
#define HAVE_MFMA16K16 1
__device__ __forceinline__ f32x4 mfma16k16(f16x4 a, f16x4 b, f32x4 c) {
    return __builtin_amdgcn_mfma_f32_16x16x16f16(a, b, c, 0, 0, 0);
}
#elif __has_builtin(__builtin_amdgcn_mfma_f32_16x16x16_f16)
#define HAVE_MFMA16K16 1
__device__ __forceinline__ f32x4 mfma16k16(f16x4 a, f16x4 b, f32x4 c) {
    return __builtin_amdgcn_mfma_f32_16x16x16_f16(a, b, c, 0, 0, 0);
}
#else
#define HAVE_MFMA16K16 0
#endif

__device__ __forceinline__ float exp2_hw(float x) {
#if __has_builtin(__builtin_amdgcn_exp2f)
    return __builtin_amdgcn_exp2f(x);
#else
    return exp2f(x);
#endif
}
__device__ __forceinline__ float fast_tanh(float x) {
    return 1.0f - 2.0f * __builtin_amdgcn_rcpf(1.0f + exp2_hw(SN * x));
}
__device__ __forceinline__ f32x4 mfma16f(f16x8 a, f16x8 b, f32x4 c) {
    return __builtin_amdgcn_mfma_f32_16x16x32_f16(a, b, c, 0, 0, 0);
}

union PU { fp16x2 h2[4]; f16x8 v; };
union GU { uint2 u; _Float16 h[4]; f16x4 v; };

__device__ __forceinline__ f16x8 pack_f16(float4 a, float4 b) {
    PU u;
    u.h2[0] = __builtin_amdgcn_cvt_pkrtz(a.x, a.y);
    u.h2[1] = __builtin_amdgcn_cvt_pkrtz(a.z, a.w);
    u.h2[2] = __builtin_amdgcn_cvt_pkrtz(b.x, b.y);
    u.h2[3] = __builtin_amdgcn_cvt_pkrtz(b.z, b.w);
    return u.v;
}

// Raw barrier: drain LDS, then s_barrier. No sched_barrier pinning --
// register-only MFMA/VALU may hoist into the barrier shadow (wanted);
// memory ops are pinned by the "memory" clobber.
__device__ __forceinline__ void wg_barrier() {
    asm volatile("s_waitcnt lgkmcnt(0)" ::: "memory");
    __builtin_amdgcn_s_barrier();
    asm volatile("" ::: "memory");
}

// ---------------- pre-GEMM: gi (fp16, prescaled, biases folded) -----------
__global__ __launch_bounds__(512)
void gi_gemm16(const float* __restrict__ x,
               const float* __restrict__ W_ih,
               const float* __restrict__ b_ih,
               const float* __restrict__ b_hh,
               uint2* __restrict__ gi)
{
    const int tid  = threadIdx.x;
    const int w    = tid >> 6;
    const int lane = tid & 63;
    const int g4   = lane >> 4;
    const int bcol = lane & 15;
    const int b0   = blockIdx.x * 16;
    const int t0   = blockIdx.y * 16;

    __shared__ __align__(16) _Float16 xt[16 * 1032 + 8];

    {
        const int bl = tid >> 5, q = tid & 31;
        const float* xp = x + ((size_t)(b0 + bl) * TSEQ + t0) * FDIM;
        _Float16* dst = &xt[bl * 1032];
        #pragma unroll
        for (int j = 0; j < 8; ++j) {
            float4 v = *(const float4*)(xp + j * 128 + q * 4);
            union { fp16x2 p[2]; uint2 u; } pu;
            pu.p[0] = __builtin_amdgcn_cvt_pkrtz(v.x, v.y);
            pu.p[1] = __builtin_amdgcn_cvt_pkrtz(v.z, v.w);
            *(uint2*)&dst[j * 128 + q * 4] = pu.u;
        }
    }

    f16x8 WihF[3][2];
    #pragma unroll
    for (int kd = 0; kd < 3; ++kd) {
        const float sc = (kd < 2) ? SR : SN;
        const int g = kd * 128 + w * 16 + bcol;
        #pragma unroll
        for (int kt = 0; kt < 2; ++kt) {
            const float* pw = W_ih + g * FDIM + kt * 32 + g4 * 8;
            f16x8 v;
            #pragma unroll
            for (int e = 0; e < 8; ++e) v[e] = (_Float16)(pw[e] * sc);
            WihF[kd][kt] = v;
        }
    }
    f32x4 biasR, biasZ, biasN;
    #pragma unroll
    for (int i = 0; i < 4; ++i) {
        const int gr = w * 16 + g4 * 4 + i;
        biasR[i] = (b_ih[gr]       + b_hh[gr])       * SR;
        biasZ[i] = (b_ih[128 + gr] + b_hh[128 + gr]) * SR;
        biasN[i] = b_ih[256 + gr] * SN;
    }
    __syncthreads();

    for (int tt = 0; tt < 16; ++tt) {
        const _Float16* xr = &xt[bcol * 1032 + tt * 64];
        f16x8 xf0 = *(const f16x8*)(xr + g4 * 8);
        f16x8 xf1 = *(const f16x8*)(xr + 32 + g4 * 8);

        f32x4 c0 = biasR, c1 = biasZ, c2 = biasN;
        c0 = mfma16f(WihF[0][0], xf0, c0);
        c0 = mfma16f(WihF[0][1], xf1, c0);
        c1 = mfma16f(WihF[1][0], xf0, c1);
        c1 = mfma16f(WihF[1][1], xf1, c1);
        c2 = mfma16f(WihF[2][0], xf0, c2);
        c2 = mfma16f(WihF[2][1], xf1, c2);

        GU g0, g1, g2;
        #pragma unroll
        for (int i = 0; i < 4; ++i) {
            g0.h[i] = (_Float16)c0[i];
            g1.h[i] = (_Float16)c1[i];
            g2.h[i] = (_Float16)c2[i];
        }
        const int t = t0 + tt;
        const size_t base = ((size_t)t * 96 + w * 4 + g4) * NB + (b0 + bcol);
        gi[base]           = g0.u;
        gi[base + 32 * NB] = g1.u;
        gi[base + 64 * NB] = g2.u;
    }
}

// ---------------- out finalize: out[b][t] = tanh(sum(pp) + b_out) ---------
__global__ __launch_bounds__(512)
void out_final(const float* __restrict__ pp,
               const float* __restrict__ b_out,
               float* __restrict__ out)
{
    const int t = blockIdx.x;
    const int b = threadIdx.x;
    float acc = b_out[0];
    const float* p = pp + (size_t)t * 32 * NB + b;
    #pragma unroll
    for (int c = 0; c < 32; ++c) acc += p[(size_t)c * NB];
    out[(size_t)b * TSEQ + t] = fast_tanh(acc);
}

// ---------------- recurrence (R13 structure, statically unrolled) ---------
// 32 blocks x 16 batches, 512 threads = 8 waves (2/SIMD).
// 12-step unrolled body (42x) + static 8-step tail: buffer indices are
// compile-time -> LDS addresses are immediate offsets, no rb/wb updates.
// gi refill via 3 running pointers; refill guard is compile-time.
// h pack via cvt_pkrtz. One lgkm-only barrier per step.
__global__ __launch_bounds__(512, 2)
void gru_rec(const float* __restrict__ W_hh,
             const float* __restrict__ b_hh,
             const float* __restrict__ W_out,
             const uint2* __restrict__ gi,
             float* __restrict__ pp)
{
    const int tid  = threadIdx.x;
    const int wid  = tid >> 6;
    const int lane = tid & 63;
    const int g4   = lane >> 4;
    const int bcol = lane & 15;
    const int b0   = blockIdx.x * 16;

    __shared__ __align__(16) _Float16 h_s[3][16][H_ROW];

    // identity A-fragment for 16x16x16 inject
    f16x4 iden;
    #pragma unroll
    for (int e = 0; e < 4; ++e)
        iden[e] = (bcol == g4 * 4 + e) ? (_Float16)1.0f : (_Float16)0.0f;
    const f32x4 zero4 = {0.f, 0.f, 0.f, 0.f};

    f16x8 WhhF[3][4];
    #pragma unroll
    for (int kd = 0; kd < 3; ++kd) {
        const float sc = (kd < 2) ? SR : SN;
        const int g = kd * 128 + wid * 16 + bcol;
        #pragma unroll
        for (int kt = 0; kt < 4; ++kt) {
            const float* pw = W_hh + g * HDIM + kt * 32 + g4 * 8;
            f16x8 v;
            #pragma unroll
            for (int e = 0; e < 8; ++e) v[e] = (_Float16)(pw[e] * sc);
            WhhF[kd][kt] = v;
        }
    }

    f32x4 biasNH;
    float wout_r[4], h_old[4];
    #pragma unroll
    for (int i = 0; i < 4; ++i) {
        const int gr = wid * 16 + g4 * 4 + i;
        biasNH[i] = b_hh[256 + gr] * SN;
        wout_r[i] = W_out[gr];
        h_old[i]  = 0.0f;
    }

    {   // zero h buffer 0
        unsigned* hp = (unsigned*)&h_s[0][0][0];
        for (int i = tid; i < H_BUF / 2; i += 512) hp[i] = 0u;
    }

    // ---- gi slots for t=0..3 + running refill pointers (t=4...) ----
    const uint2* gB = gi + ((size_t)wid * 4 + g4) * NB + (b0 + bcol);
    GU r0s, z0s, n0s, r1s, z1s, n1s, r2s, z2s, n2s, r3s, z3s, n3s;
    r0s.u = gB[0];              z0s.u = gB[32 * NB];          n0s.u = gB[64 * NB];
    r1s.u = gB[1*G_STEP];       z1s.u = gB[1*G_STEP + 32*NB]; n1s.u = gB[1*G_STEP + 64*NB];
    r2s.u = gB[2*G_STEP];       z2s.u = gB[2*G_STEP + 32*NB]; n2s.u = gB[2*G_STEP + 64*NB];
    r3s.u = gB[3*G_STEP];       z3s.u = gB[3*G_STEP + 32*NB]; n3s.u = gB[3*G_STEP + 64*NB];
    const uint2* gPr = gB + 4 * G_STEP;
    const uint2* gPz = gPr + 32 * NB;
    const uint2* gPn = gPr + 64 * NB;

    float* ppp = pp + ((size_t)wid * 4 + g4) * NB + (b0 + bcol);

    const _Float16* hrd = &h_s[0][bcol][0];
    _Float16*       hwr = &h_s[0][bcol][wid * 16 + g4 * 4];

    __syncthreads();   // prologue barrier

#if HAVE_MFMA16K16
#define INJ(S) mfma16k16(iden, S.v, zero4)
#else
#define INJ(S) (f32x4){(float)S.h[0], (float)S.h[1], (float)S.h[2], (float)S.h[3]}
#endif

#define STEP(RB, WB, SL, RF)                                                  \
{                                                                             \
    f16x8 bh0 = *(const f16x8*)(hrd + (RB) * H_BUF + 0 * 32 + g4 * 8);        \
    f16x8 bh1 = *(const f16x8*)(hrd + (RB) * H_BUF + 1 * 32 + g4 * 8);        \
    f16x8 bh2 = *(const f16x8*)(hrd + (RB) * H_BUF + 2 * 32 + g4 * 8);        \
    f16x8 bh3 = *(const f16x8*)(hrd + (RB) * H_BUF + 3 * 32 + g4 * 8);        \
    f32x4 a0 = INJ(r##SL##s);                                                 \
    f32x4 a1 = INJ(z##SL##s);                                                 \
    f32x4 a2 = INJ(n##SL##s);                                                 \
    if (RF) {                                                                 \
        r##SL##s.u = *gPr; z##SL##s.u = *gPz; n##SL##s.u = *gPn;              \
        gPr += G_STEP; gPz += G_STEP; gPn += G_STEP;                          \
    }                                                                         \
    f32x4 a3 = biasNH;                                                        \
    a0 = mfma16f(WhhF[0][0], bh0, a0);                                        \
    a1 = mfma16f(WhhF[1][0], bh0, a1);                                        \
    a3 = mfma16f(WhhF[2][0], bh0, a3);                                        \
    a0 = mfma16f(WhhF[0][1], bh1, a0);                                        \
    a1 = mfma16f(WhhF[1][1], bh1, a1);                                        \
    a3 = mfma16f(WhhF[2][1], bh1, a3);                                        \
    a0 = mfma16f(WhhF[0][2], bh2, a0);                                        \
    a1 = mfma16f(WhhF[1][2], bh2, a1);                                        \
    a3 = mfma16f(WhhF[2][2], bh2, a3);                                        \
    a0 = mfma16f(WhhF[0][3], bh3, a0);                                        \
    a1 = mfma16f(WhhF[1][3], bh3, a1);                                        \
    a3 = mfma16f(WhhF[2][3], bh3, a3);                                        \
    float psum = 0.0f;                                                        \
    float hn[4];                                                              \
    _Pragma("unroll")                                                         \
    for (int i = 0; i < 4; ++i) {                                             \
        float r = __builtin_amdgcn_rcpf(1.0f + exp2_hw(-a0[i]));              \
        float z = __builtin_amdgcn_rcpf(1.0f + exp2_hw(-a1[i]));              \
        float y = fmaf(r, a3[i], a2[i]);                                      \
        float n = fmaf(-2.0f, __builtin_amdgcn_rcpf(1.0f + exp2_hw(y)), 1.0f);\
        hn[i] = fmaf(z, h_old[i] - n, n);                                     \
        h_old[i] = hn[i];                                                     \
        psum = fmaf(wout_r[i], hn[i], psum);                                  \
    }                                                                         \
    {                                                                         \
        union { fp16x2 p[2]; uint2 u; } hu;                                   \
        hu.p[0] = __builtin_amdgcn_cvt_pkrtz(hn[0], hn[1]);                   \
        hu.p[1] = __builtin_amdgcn_cvt_pkrtz(hn[2], hn[3]);                   \
        *(uint2*)(hwr + (WB) * H_BUF) = hu.u;                                 \
    }                                                                         \
    *ppp = psum;                                                              \
    ppp += 32 * NB;                                                           \
    wg_barrier();                                                             \
}

    // 42 x 12 = 504 steps with compile-time buffer phases
    for (int tt = 0; tt < 42; ++tt) {
        STEP(0,1,0,1) STEP(1,2,1,1) STEP(2,0,2,1) STEP(0,1,3,1)
        STEP(1,2,0,1) STEP(2,0,1,1) STEP(0,1,2,1) STEP(1,2,3,1)
        STEP(2,0,0,1) STEP(0,1,1,1) STEP(1,2,2,1) STEP(2,0,3,1)
    }
    // tail: s = 504..511 (504 % 3 == 0, 504 % 4 == 0)
    STEP(0,1,0,1) STEP(1,2,1,1) STEP(2,0,2,1) STEP(0,1,3,1)
    STEP(1,2,0,0) STEP(2,0,1,0) STEP(0,1,2,0) STEP(1,2,3,0)

#undef STEP
#undef INJ
}

// ---------------- fallback (no workspace): R9-proven unified kernel -------
__global__ __launch_bounds__(512, 2)
void gru_fb(const float* __restrict__ x,
            const float* __restrict__ W_ih,
            const float* __restrict__ W_hh,
            const float* __restrict__ b_ih,
            const float* __restrict__ b_hh,
            const float* __restrict__ W_out,
            const float* __restrict__ b_out,
            float* __restrict__ out)
{
    const int tid  = threadIdx.x;
    const int wid  = tid >> 6;
    const int lane = tid & 63;
    const int g4   = lane >> 4;
    const int bcol = lane & 15;
    const int b0   = blockIdx.x * 16;

    __shared__ __align__(16) _Float16 h_s[3][16][H_ROW];
    __shared__ __align__(16) float ps_s[3][16][12];

    f16x8 WhhF[3][4];
    f16x8 WihF[3][2];
    #pragma unroll
    for (int kd = 0; kd < 3; ++kd) {
        const float sc = (kd < 2) ? SR : SN;
        const int g = kd * 128 + wid * 16 + bcol;
        #pragma unroll
        for (int kt = 0; kt < 4; ++kt) {
            const float* pw = W_hh + g * HDIM + kt * 32 + g4 * 8;
            f16x8 v;
            #pragma unroll
            for (int e = 0; e < 8; ++e) v[e] = (_Float16)(pw[e] * sc);
            WhhF[kd][kt] = v;
        }
        #pragma unroll
        for (int kt = 0; kt < 2; ++kt) {
            const float* pw = W_ih + g * FDIM + kt * 32 + g4 * 8;
            f16x8 v;
            #pragma unroll
            for (int e = 0; e < 8; ++e) v[e] = (_Float16)(pw[e] * sc);
            WihF[kd][kt] = v;
        }
    }

    f32x4 biasR, biasZ, biasNI, biasNH;
    float wout_r[4], h_old[4];
    #pragma unroll
    for (int i = 0; i < 4; ++i) {
        const int gr = wid * 16 + g4 * 4 + i;
        biasR[i]  = (b_ih[gr]       + b_hh[gr])       * SR;
        biasZ[i]  = (b_ih[128 + gr] + b_hh[128 + gr]) * SR;
        biasNI[i] = b_ih[256 + gr] * SN;
        biasNH[i] = b_hh[256 + gr] * SN;
        wout_r[i] = W_out[gr];
        h_old[i]  = 0.0f;
    }
    const float bout = b_out[0];

    {
        unsigned* hp = (unsigned*)&h_s[0][0][0];
        for (int i = tid; i < H_BUF / 2; i += 512) hp[i] = 0u;
    }

    const float* xb = x + (size_t)(b0 + bcol) * TSEQ * FDIM;
    float4 sA0, sA1, sA2, sA3, sB0, sB1, sB2, sB3;
    sA0 = *(const float4*)(xb + g4 * 8);
    sA1 = *(const float4*)(xb + g4 * 8 + 4);
    sA2 = *(const float4*)(xb + 32 + g4 * 8);
    sA3 = *(const float4*)(xb + 32 + g4 * 8 + 4);
    {
        const float* xp1 = xb + FDIM;
        sB0 = *(const float4*)(xp1 + g4 * 8);
        sB1 = *(const float4*)(xp1 + g4 * 8 + 4);
        sB2 = *(const float4*)(xp1 + 32 + g4 * 8);
        sB3 = *(const float4*)(xp1 + 32 + g4 * 8 + 4);
    }
    f16x8 xf0 = pack_f16(sA0, sA1);
    f16x8 xf1 = pack_f16(sA2, sA3);

    __syncthreads();

    const bool outw = (wid == 0) && (lane < 16);
    float* outp = out + (size_t)(b0 + lane) * TSEQ;
    float o0 = 0.f, o1 = 0.f, o2 = 0.f, o3 = 0.f;
    int rb = 0, wb = 1;

    for (int t = 0; t < TSEQ; t += 4) {
        #pragma unroll
        for (int u = 0; u < 4; ++u) {
            const int s = t + u;

            if (outw && s > 0) {
                f32x4 q0 = *(const f32x4*)&ps_s[rb][lane][0];
                f32x4 q1 = *(const f32x4*)&ps_s[rb][lane][4];
                float sm = (q0[0] + q0[1]) + (q0[2] + q0[3])
                         + (q1[0] + q1[1]) + (q1[2] + q1[3]);
                float val = fast_tanh(sm + bout);
                if (u == 0) {
                    o3 = val;
                    *(float4*)(outp + (t - 4)) = make_float4(o0, o1, o2, o3);
                } else if (u == 1) o0 = val;
                else if (u == 2) o1 = val;
                else o2 = val;
            }

            {
                const int tl = (s + 2 < TSEQ) ? (s + 2) : (TSEQ - 1);
                const float* xp = xb + (size_t)tl * FDIM;
                if ((u & 1) == 0) {
                    sA0 = *(const float4*)(xp + g4 * 8);
                    sA1 = *(const float4*)(xp + g4 * 8 + 4);
                    sA2 = *(const float4*)(xp + 32 + g4 * 8);
                    sA3 = *(const float4*)(xp + 32 + g4 * 8 + 4);
                } else {
                    sB0 = *(const float4*)(xp + g4 * 8);
                    sB1 = *(const float4*)(xp + g4 * 8 + 4);
                    sB2 = *(const float4*)(xp + 32 + g4 * 8);
                    sB3 = *(const float4*)(xp + 32 + g4 * 8 + 4);
                }
            }
            f16x8 bh0 = *(const f16x8*)&h_s[rb][bcol][0 * 32 + g4 * 8];
            f16x8 bh1 = *(const f16x8*)&h_s[rb][bcol][1 * 32 + g4 * 8];
            f16x8 bh2 = *(const f16x8*)&h_s[rb][bcol][2 * 32 + g4 * 8];
            f16x8 bh3 = *(const f16x8*)&h_s[rb][bcol][3 * 32 + g4 * 8];

            f32x4 a0 = biasR, a1 = biasZ, a2 = biasNI, a3 = biasNH;
            a0 = mfma16f(WihF[0][0], xf0, a0);
            a0 = mfma16f(WihF[0][1], xf1, a0);
            a1 = mfma16f(WihF[1][0], xf0, a1);
            a1 = mfma16f(WihF[1][1], xf1, a1);
            a2 = mfma16f(WihF[2][0], xf0, a2);
            a2 = mfma16f(WihF[2][1], xf1, a2);

            a0 = mfma16f(WhhF[0][0], bh0, a0);
            a1 = mfma16f(WhhF[1][0], bh0, a1);
            a3 = mfma16f(WhhF[2][0], bh0, a3);
            a0 = mfma16f(WhhF[0][1], bh1, a0);
            a1 = mfma16f(WhhF[1][1], bh1, a1);
            a3 = mfma16f(WhhF[2][1], bh1, a3);
            a0 = mfma16f(WhhF[0][2], bh2, a0);
            a1 = mfma16f(WhhF[1][2], bh2, a1);
            a3 = mfma16f(WhhF[2][2], bh2, a3);
            a0 = mfma16f(WhhF[0][3], bh3, a0);
            a1 = mfma16f(WhhF[1][3], bh3, a1);
            a3 = mfma16f(WhhF[2][3], bh3, a3);

            float psum = 0.0f;
            _Float16 h16[4];
            #pragma unroll
            for (int i = 0; i < 4; ++i) {
                float r  = __builtin_amdgcn_rcpf(1.0f + exp2_hw(-a0[i]));
                float z  = __builtin_amdgcn_rcpf(1.0f + exp2_hw(-a1[i]));
                float y  = fmaf(r, a3[i], a2[i]);
                float n  = fmaf(-2.0f,
                                __builtin_amdgcn_rcpf(1.0f + exp2_hw(y)), 1.0f);
                float hn = fmaf(z, h_old[i] - n, n);
                h_old[i] = hn;
                h16[i]   = (_Float16)hn;
                psum = fmaf(wout_r[i], hn, psum);
            }

            union { _Float16 h[4]; uint2 u; } hu;
            hu.h[0] = h16[0]; hu.h[1] = h16[1];
            hu.h[2] = h16[2]; hu.h[3] = h16[3];
            *(uint2*)&h_s[wb][bcol][wid * 16 + g4 * 4] = hu.u;

            psum += __shfl_xor(psum, 16);
            psum += __shfl_xor(psum, 32);
            if (lane < 16) ps_s[wb][lane][wid] = psum;

            if ((u & 1) == 0) {
                xf0 = pack_f16(sB0, sB1);
                xf1 = pack_f16(sB2, sB3);
            } else {
                xf0 = pack_f16(sA0, sA1);
                xf1 = pack_f16(sA2, sA3);
            }

            wg_barrier();
            rb = wb; wb = (wb == 2) ? 0 : wb + 1;
        }
    }

    if (outw) {
        f32x4 q0 = *(const f32x4*)&ps_s[2][lane][0];
        f32x4 q1 = *(const f32x4*)&ps_s[2][lane][4];
        float sm = (q0[0] + q0[1]) + (q0[2] + q0[3])
                 + (q1[0] + q1[1]) + (q1[2] + q1[3]);
        o3 = fast_tanh(sm + bout);
        *(float4*)(outp + (TSEQ - 4)) = make_float4(o0, o1, o2, o3);
    }
}

extern "C" void kernel_launch(void* const* d_in, const int* in_sizes, int n_in,
                              void* d_out, int out_size, void* d_ws, size_t ws_size,
                              hipStream_t stream) {
    const float* x     = (const float*)d_in[0];
    const float* W_ih  = (const float*)d_in[1];
    const float* W_hh  = (const float*)d_in[2];
    const float* b_ih  = (const float*)d_in[3];
    const float* b_hh  = (const float*)d_in[4];
    const float* W_out = (const float*)d_in[5];
    const float* b_out = (const float*)d_in[6];
    float* out = (float*)d_out;

    const size_t gi_bytes = (size_t)TSEQ * NB * 384 * sizeof(_Float16); // 201.3 MB
    const size_t pp_bytes = (size_t)TSEQ * 32 * NB * sizeof(float);     // 33.6 MB

    if (ws_size >= gi_bytes + pp_bytes) {
        uint2* gi = (uint2*)d_ws;
        float* pp = (float*)((char*)d_ws + gi_bytes);
        gi_gemm16<<<dim3(32, 32), 512, 0, stream>>>(x, W_ih, b_ih, b_hh, gi);
        gru_rec<<<32, 512, 0, stream>>>(W_hh, b_hh, W_out, gi, pp);
        out_final<<<TSEQ, NB, 0, stream>>>(pp, b_out, out);
    } else {
        gru_fb<<<32, 512, 0, stream>>>(x, W_ih, W_hh, b_ih, b_hh,
                                       W_out, b_out, out);
    }
}